// Round 3
// baseline (1379.441 us; speedup 1.0000x reference)
//
#include <hip/hip_runtime.h>
#include <hip/hip_bf16.h>

// Problem constants
#define NB 16
#define ND 512
#define NT 2048
#define TM1 2047
#define NHD 256
#define QSTRIDE 2048ull  // QD row stride padded 2047->2048 for float4 alignment

// ws layout (float offsets) — small head FIRST, big QD ring after.
#define G0_OFF   0ull
#define G0_ELEMS (16ull * 2047ull)       // 32,752 floats
#define WSUM_OFF (G0_OFF + G0_ELEMS)     // 1 float
#define R_OFF    32768ull                // aligned
#define R_ELEMS  (16ull * 1024ull)       // 16,384 floats
#define HEAD_FLOATS 49152ull             // 192 KB head scratch
#define QD_BATCH_FLOATS (512ull * QSTRIDE)  // 4 MB per batch

// --- Wsum = sum_t W_out[-1][t] ------------------------------------------
__global__ __launch_bounds__(256) void k_wsum(const float* __restrict__ wlast,
                                              float* __restrict__ wsum) {
    __shared__ float red[256];
    float s = 0.f;
    for (int t = threadIdx.x; t < NT; t += 256) s += wlast[t];
    red[threadIdx.x] = s;
    __syncthreads();
    for (int off = 128; off > 0; off >>= 1) {
        if (threadIdx.x < off) red[threadIdx.x] += red[threadIdx.x + off];
        __syncthreads();
    }
    if (threadIdx.x == 0) *wsum = red[0];
}

// --- QD[c][j][s] = sign_j * sum_d xs[b,d,s] * W_KQ[d,j],  b = b0+c -------
// M=j (512), N=s (2048 incl. pad col), K=d (512). 64x64 tile, BK=16, 4x4/thr.
__global__ __launch_bounds__(256) void k_qd(const float* __restrict__ xs,
                                            const float* __restrict__ wkq,
                                            float* __restrict__ qd, int b0) {
    const int j0 = blockIdx.x * 64;
    const int s0 = blockIdx.y * 64;
    const int c  = blockIdx.z;
    const int b  = b0 + c;
    __shared__ float As[16][64];  // [d][j]
    __shared__ float Bs[16][64];  // [d][s]
    const int tid = threadIdx.x;
    const int ty = tid >> 4, tx = tid & 15;
    const int lr = tid >> 4;          // load row (d) 0..15
    const int lc = (tid & 15) * 4;    // load col *4
    const float* xb = xs + (size_t)b * ND * NT;
    float acc[4][4] = {};
    for (int kt = 0; kt < 32; ++kt) {
        const int d0 = kt * 16;
        *(float4*)&As[lr][lc] = *(const float4*)&wkq[(size_t)(d0 + lr) * ND + j0 + lc];
        *(float4*)&Bs[lr][lc] = *(const float4*)&xb[(size_t)(d0 + lr) * NT + s0 + lc];
        __syncthreads();
        #pragma unroll
        for (int k = 0; k < 16; ++k) {
            const float4 a4 = *(const float4*)&As[k][ty * 4];
            const float4 b4 = *(const float4*)&Bs[k][tx * 4];
            const float ar[4] = {a4.x, a4.y, a4.z, a4.w};
            const float br[4] = {b4.x, b4.y, b4.z, b4.w};
            #pragma unroll
            for (int i = 0; i < 4; ++i)
                #pragma unroll
                for (int j = 0; j < 4; ++j)
                    acc[i][j] = fmaf(ar[i], br[j], acc[i][j]);
        }
        __syncthreads();
    }
    #pragma unroll
    for (int i = 0; i < 4; ++i) {
        const int jg = j0 + ty * 4 + i;
        const float sgn = (jg < NHD) ? 1.f : -1.f;
        float* qrow = qd + ((size_t)c * ND + jg) * QSTRIDE;
        #pragma unroll
        for (int j = 0; j < 4; ++j) {
            const int sg = s0 + tx * 4 + j;
            qrow[sg] = sgn * acc[i][j];   // pad col s=2047 written too (discarded later)
        }
    }
}

// --- g0[b,s] += sum_t sigmoid(Delta[b,s,t]) * w[t],  b = b0+c ------------
// Delta[b,s,t] = sum_d QD[c,d,s] * xs[b,d,t]. Never materializes Delta.
__global__ __launch_bounds__(256) void k_attn(const float* __restrict__ xs,
                                              const float* __restrict__ qd,
                                              const float* __restrict__ wlast,
                                              float* __restrict__ g0, int b0) {
    const int th = blockIdx.x;        // t-half: [th*1024, th*1024+1024)
    const int s0 = blockIdx.y * 64;
    const int c  = blockIdx.z;
    const int b  = b0 + c;
    __shared__ float As[16][64];  // [d][s]
    __shared__ float Bs[16][64];  // [d][t]
    __shared__ float gl[64][17];
    const int tid = threadIdx.x;
    const int ty = tid >> 4, tx = tid & 15;
    const int lr = tid >> 4;
    const int lc = (tid & 15) * 4;
    const float* xb = xs + (size_t)b * ND * NT;
    const float* qb = qd + (size_t)c * ND * QSTRIDE;
    float gpart[4] = {0.f, 0.f, 0.f, 0.f};
    for (int tt = 0; tt < 16; ++tt) {
        const int t0 = th * 1024 + tt * 64;
        float acc[4][4] = {};
        for (int kt = 0; kt < 32; ++kt) {
            const int d0 = kt * 16;
            *(float4*)&As[lr][lc] = *(const float4*)&qb[(size_t)(d0 + lr) * QSTRIDE + s0 + lc];
            *(float4*)&Bs[lr][lc] = *(const float4*)&xb[(size_t)(d0 + lr) * NT + t0 + lc];
            __syncthreads();
            #pragma unroll
            for (int k = 0; k < 16; ++k) {
                const float4 a4 = *(const float4*)&As[k][ty * 4];
                const float4 b4 = *(const float4*)&Bs[k][tx * 4];
                const float ar[4] = {a4.x, a4.y, a4.z, a4.w};
                const float br[4] = {b4.x, b4.y, b4.z, b4.w};
                #pragma unroll
                for (int i = 0; i < 4; ++i)
                    #pragma unroll
                    for (int j = 0; j < 4; ++j)
                        acc[i][j] = fmaf(ar[i], br[j], acc[i][j]);
            }
            __syncthreads();
        }
        #pragma unroll
        for (int j = 0; j < 4; ++j) {
            const float wt = wlast[t0 + tx * 4 + j];
            #pragma unroll
            for (int i = 0; i < 4; ++i) {
                const float sg = 1.f / (1.f + __expf(-acc[i][j]));
                gpart[i] = fmaf(sg, wt, gpart[i]);
            }
        }
    }
    #pragma unroll
    for (int i = 0; i < 4; ++i) gl[ty * 4 + i][tx] = gpart[i];
    __syncthreads();
    if (tid < 64) {
        float s = 0.f;
        #pragma unroll
        for (int x = 0; x < 16; ++x) s += gl[tid][x];
        const int sg = s0 + tid;
        if (sg < TM1) atomicAdd(&g0[b * TM1 + sg], s);
    }
}

// --- r[b,0,d] = sum_s xs[b,d,s]*g0[b,s]; r[b,1,d] = Wsum*sum_s xs - r0 ---
__global__ __launch_bounds__(256) void k_r(const float* __restrict__ xs,
                                           const float* __restrict__ g0,
                                           const float* __restrict__ wsum,
                                           float* __restrict__ r) {
    const int d = blockIdx.x;
    const int b = blockIdx.y;
    const float* xrow = xs + ((size_t)b * ND + d) * NT;
    const float* g = g0 + b * TM1;
    float a0 = 0.f, a1 = 0.f;
    for (int s = threadIdx.x; s < TM1; s += 256) {
        const float x = xrow[s];
        a0 = fmaf(x, g[s], a0);
        a1 += x;
    }
    #pragma unroll
    for (int off = 32; off > 0; off >>= 1) {
        a0 += __shfl_down(a0, off);
        a1 += __shfl_down(a1, off);
    }
    __shared__ float l0[4], l1[4];
    const int wid = threadIdx.x >> 6;
    if ((threadIdx.x & 63) == 0) { l0[wid] = a0; l1[wid] = a1; }
    __syncthreads();
    if (threadIdx.x == 0) {
        const float sum0 = l0[0] + l0[1] + l0[2] + l0[3];
        const float sumx = l1[0] + l1[1] + l1[2] + l1[3];
        const float wsv = *wsum;
        r[((size_t)b * 2 + 0) * ND + d] = sum0;
        r[((size_t)b * 2 + 1) * ND + d] = fmaf(wsv, sumx, -sum0);
    }
}

// --- out[b,i] = sum_d W_PV[i,d] * r[b, i/256, d]  (fp32 out) -------------
__global__ __launch_bounds__(256) void k_out(const float* __restrict__ wpv,
                                             const float* __restrict__ r,
                                             float* __restrict__ out) {
    const int b = blockIdx.x;
    __shared__ float rs[1024];
    for (int i = threadIdx.x; i < 1024; i += 256) rs[i] = r[(size_t)b * 1024 + i];
    __syncthreads();
    for (int i = threadIdx.x; i < ND; i += 256) {
        const float* wrow = wpv + (size_t)i * ND;
        const float* rh = rs + (i >> 8) * ND;
        float acc = 0.f;
        for (int dd = 0; dd < ND; dd += 4) {
            const float4 wv = *(const float4*)(wrow + dd);
            acc += wv.x * rh[dd] + wv.y * rh[dd + 1] + wv.z * rh[dd + 2] + wv.w * rh[dd + 3];
        }
        out[b * ND + i] = acc;   // fp32 output (reference output dtype is float32)
    }
}

extern "C" void kernel_launch(void* const* d_in, const int* in_sizes, int n_in,
                              void* d_out, int out_size, void* d_ws, size_t ws_size,
                              hipStream_t stream) {
    (void)in_sizes; (void)n_in; (void)out_size;
    const float* xs   = (const float*)d_in[0];
    const float* wkq  = (const float*)d_in[1];
    const float* wpv  = (const float*)d_in[2];
    const float* wout = (const float*)d_in[3];
    const float* wlast = wout + (size_t)(NT - 1) * NT;  // W_out[-1]

    float* ws   = (float*)d_ws;
    float* g0   = ws + G0_OFF;
    float* wsum = ws + WSUM_OFF;
    float* r    = ws + R_OFF;
    float* qd   = ws + HEAD_FLOATS;

    // Batch-chunk the 4 MB/batch QD scratch to whatever ws_size allows.
    const size_t ws_floats = ws_size / 4;
    size_t avail = (ws_floats > HEAD_FLOATS) ? (ws_floats - HEAD_FLOATS) : 0;
    int C = (int)(avail / QD_BATCH_FLOATS);
    if (C > NB) C = NB;
    if (C < 1) C = 1;  // last resort; needs >= ~4.2 MB ws

    hipMemsetAsync(g0, 0, G0_ELEMS * sizeof(float), stream);
    k_wsum<<<1, 256, 0, stream>>>(wlast, wsum);
    for (int b0 = 0; b0 < NB; b0 += C) {
        const int cb = (NB - b0 < C) ? (NB - b0) : C;
        k_qd  <<<dim3(8, 32, cb), 256, 0, stream>>>(xs, wkq, qd, b0);
        k_attn<<<dim3(2, 32, cb), 256, 0, stream>>>(xs, qd, wlast, g0, b0);
    }
    k_r   <<<dim3(ND, NB), 256, 0, stream>>>(xs, g0, wsum, r);
    k_out <<<NB, 256, 0, stream>>>(wpv, r, (float*)d_out);
}

// Round 5
// 372.291 us; speedup vs baseline: 3.7053x; 3.7053x over previous
//
#include <hip/hip_runtime.h>
#include <hip/hip_bf16.h>

// Problem constants
#define NB 16
#define ND 512
#define NT 2048
#define TM1 2047
#define NHD 256

typedef __attribute__((ext_vector_type(8))) short bf16x8;
typedef __attribute__((ext_vector_type(4))) float f32x4;
typedef unsigned short ushort_t;
typedef unsigned int uint_t;

// ws layout (float offsets): head scratch, wkqT, then per-chunk qdb/xst.
#define G0_OFF    0ull
#define G0_ELEMS  (16ull * 2047ull)
#define WSUM_OFF  32752ull
#define R_OFF     32768ull
#define WKQT_OFF  49152ull                 // 512*512 bf16 = 131072 floats
#define CHUNK_OFF 180224ull
#define BATCH_US  (2048ull * 512ull)       // ushorts per batch per array (2 MB)
#define BATCH_FLOATS (2ull * 524288ull)    // qdb + xst floats per batch (4 MB)

__device__ __forceinline__ ushort_t f2bf(float x) {
    union { float f; uint_t u; } v; v.f = x;
    uint_t r = v.u + 0x7FFFu + ((v.u >> 16) & 1u);  // round-to-nearest-even
    return (ushort_t)(r >> 16);
}

// --- Wsum = sum_t W_out[-1][t] ------------------------------------------
__global__ __launch_bounds__(256) void k_wsum(const float* __restrict__ wlast,
                                              float* __restrict__ wsum) {
    __shared__ float red[256];
    float s = 0.f;
    for (int t = threadIdx.x; t < NT; t += 256) s += wlast[t];
    red[threadIdx.x] = s;
    __syncthreads();
    for (int off = 128; off > 0; off >>= 1) {
        if (threadIdx.x < off) red[threadIdx.x] += red[threadIdx.x + off];
        __syncthreads();
    }
    if (threadIdx.x == 0) *wsum = red[0];
}

// --- wkqT[j][d] = bf16(wkq[d][j]) ---------------------------------------
__global__ __launch_bounds__(256) void k_cvt_wkq(const float* __restrict__ wkq,
                                                 ushort_t* __restrict__ wkqT) {
    __shared__ float tile[32][33];
    const int j0 = blockIdx.x * 32, d0 = blockIdx.y * 32;
    const int c = threadIdx.x & 31, r = threadIdx.x >> 5;  // r in 0..7
    #pragma unroll
    for (int i = 0; i < 4; ++i) {
        const int d = r + i * 8;
        tile[d][c] = wkq[(size_t)(d0 + d) * ND + j0 + c];
    }
    __syncthreads();
    #pragma unroll
    for (int i = 0; i < 4; ++i) {
        const int j = r + i * 8;
        wkqT[(size_t)(j0 + j) * ND + d0 + c] = f2bf(tile[c][j]);
    }
}

// --- xst[c][t][d] = bf16(xs[b0+c][d][t]) --------------------------------
__global__ __launch_bounds__(256) void k_cvt_xst(const float* __restrict__ xs,
                                                 ushort_t* __restrict__ xst, int b0) {
    __shared__ float tile[32][33];
    const int t0 = blockIdx.x * 32, d0 = blockIdx.y * 32;
    const int cc = blockIdx.z;
    const int b = b0 + cc;
    const int c = threadIdx.x & 31, r = threadIdx.x >> 5;
    const float* xb = xs + (size_t)b * ND * NT;
    ushort_t* xo = xst + (size_t)cc * BATCH_US;
    #pragma unroll
    for (int i = 0; i < 4; ++i) {
        const int d = r + i * 8;
        tile[d][c] = xb[(size_t)(d0 + d) * NT + t0 + c];
    }
    __syncthreads();
    #pragma unroll
    for (int i = 0; i < 4; ++i) {
        const int t = r + i * 8;
        xo[(size_t)(t0 + t) * ND + d0 + c] = f2bf(tile[c][t]);
    }
}

// --- qdb[c][s][j] = bf16( sign_j * sum_d xst[c][s][d] * wkqT[j][d] ) -----
// MFMA GEMM: M=s(128/block), N=j(128/block), K=512. 4 waves, 64x64/wave.
__global__ __launch_bounds__(256) void k_qd(const ushort_t* __restrict__ xst,
                                            const ushort_t* __restrict__ wkqT,
                                            ushort_t* __restrict__ qdb) {
    const int j0 = blockIdx.x * 128;
    const int s0 = blockIdx.y * 128;
    const int cc = blockIdx.z;
    __shared__ __align__(16) ushort_t As[128][72];  // [s][d], +8 pad
    __shared__ __align__(16) ushort_t Bs[128][72];  // [j][d], +8 pad
    const int tid = threadIdx.x;
    const int wave = tid >> 6, lane = tid & 63;
    const int l15 = lane & 15, quad = lane >> 4;
    const int wm = wave >> 1, wn = wave & 1;
    const ushort_t* xa = xst + (size_t)cc * BATCH_US;
    ushort_t* qo = qdb + (size_t)cc * BATCH_US;
    f32x4 acc[4][4];
    #pragma unroll
    for (int mi = 0; mi < 4; ++mi)
        #pragma unroll
        for (int nj = 0; nj < 4; ++nj) acc[mi][nj] = (f32x4){0.f, 0.f, 0.f, 0.f};
    for (int ks = 0; ks < 8; ++ks) {
        const int k0 = ks * 64;
        for (int i = tid; i < 1024; i += 256) {       // full 128x64 tile
            const int row = i >> 3, ch = i & 7;
            *(uint4*)&As[row][ch * 8] = *(const uint4*)(xa + (size_t)(s0 + row) * ND + k0 + ch * 8);
            *(uint4*)&Bs[row][ch * 8] = *(const uint4*)(wkqT + (size_t)(j0 + row) * ND + k0 + ch * 8);
        }
        __syncthreads();
        #pragma unroll
        for (int kc = 0; kc < 2; ++kc) {
            bf16x8 af[4], bfr[4];
            #pragma unroll
            for (int mi = 0; mi < 4; ++mi)
                af[mi] = *(const bf16x8*)&As[wm * 64 + mi * 16 + l15][kc * 32 + quad * 8];
            #pragma unroll
            for (int nj = 0; nj < 4; ++nj)
                bfr[nj] = *(const bf16x8*)&Bs[wn * 64 + nj * 16 + l15][kc * 32 + quad * 8];
            #pragma unroll
            for (int mi = 0; mi < 4; ++mi)
                #pragma unroll
                for (int nj = 0; nj < 4; ++nj)
                    acc[mi][nj] = __builtin_amdgcn_mfma_f32_16x16x32_bf16(af[mi], bfr[nj], acc[mi][nj], 0, 0, 0);
        }
        __syncthreads();
    }
    // Epilogue: sign by head, store bf16 (C/D: row=quad*4+r, col=l15)
    #pragma unroll
    for (int mi = 0; mi < 4; ++mi) {
        const int srow = s0 + wm * 64 + mi * 16 + quad * 4;
        #pragma unroll
        for (int nj = 0; nj < 4; ++nj) {
            const int jcol = j0 + wn * 64 + nj * 16 + l15;
            const float sgn = (jcol < NHD) ? 1.f : -1.f;
            #pragma unroll
            for (int r = 0; r < 4; ++r)
                qo[(size_t)(srow + r) * ND + jcol] = f2bf(sgn * acc[mi][nj][r]);
        }
    }
}

// --- g0[b,s] += sum_t sigmoid(Delta[b,s,t]) * w[t] -----------------------
// Delta = qdb[s][:] . xst[t][:] (K=512).  Block: 128 s x 1024 t (8 tiles).
__global__ __launch_bounds__(256) void k_attn(const ushort_t* __restrict__ qdb,
                                              const ushort_t* __restrict__ xst,
                                              const float* __restrict__ wlast,
                                              float* __restrict__ g0, int b0) {
    const int th = blockIdx.x;            // t-half
    const int s0 = blockIdx.y * 128;
    const int cc = blockIdx.z;
    const int b = b0 + cc;
    __shared__ __align__(16) ushort_t As[128][72];  // [s][j]
    __shared__ __align__(16) ushort_t Bs[128][72];  // [t][j]
    const int tid = threadIdx.x;
    const int wave = tid >> 6, lane = tid & 63;
    const int l15 = lane & 15, quad = lane >> 4;
    const int wm = wave >> 1, wn = wave & 1;
    const ushort_t* qa = qdb + (size_t)cc * BATCH_US;
    const ushort_t* xa = xst + (size_t)cc * BATCH_US;
    float gp[4][4] = {};
    for (int tt = 0; tt < 8; ++tt) {
        const int t0 = th * 1024 + tt * 128;
        f32x4 acc[4][4];
        #pragma unroll
        for (int mi = 0; mi < 4; ++mi)
            #pragma unroll
            for (int nj = 0; nj < 4; ++nj) acc[mi][nj] = (f32x4){0.f, 0.f, 0.f, 0.f};
        for (int ks = 0; ks < 8; ++ks) {
            const int k0 = ks * 64;
            for (int i = tid; i < 1024; i += 256) {   // full 128x64 tile
                const int row = i >> 3, ch = i & 7;
                *(uint4*)&As[row][ch * 8] = *(const uint4*)(qa + (size_t)(s0 + row) * ND + k0 + ch * 8);
                *(uint4*)&Bs[row][ch * 8] = *(const uint4*)(xa + (size_t)(t0 + row) * ND + k0 + ch * 8);
            }
            __syncthreads();
            #pragma unroll
            for (int kc = 0; kc < 2; ++kc) {
                bf16x8 af[4], bfr[4];
                #pragma unroll
                for (int mi = 0; mi < 4; ++mi)
                    af[mi] = *(const bf16x8*)&As[wm * 64 + mi * 16 + l15][kc * 32 + quad * 8];
                #pragma unroll
                for (int nj = 0; nj < 4; ++nj)
                    bfr[nj] = *(const bf16x8*)&Bs[wn * 64 + nj * 16 + l15][kc * 32 + quad * 8];
                #pragma unroll
                for (int mi = 0; mi < 4; ++mi)
                    #pragma unroll
                    for (int nj = 0; nj < 4; ++nj)
                        acc[mi][nj] = __builtin_amdgcn_mfma_f32_16x16x32_bf16(af[mi], bfr[nj], acc[mi][nj], 0, 0, 0);
            }
            __syncthreads();
        }
        // fold sigmoid * w[t] into per-row partials
        #pragma unroll
        for (int nj = 0; nj < 4; ++nj) {
            const float wt = wlast[t0 + wn * 64 + nj * 16 + l15];
            #pragma unroll
            for (int mi = 0; mi < 4; ++mi)
                #pragma unroll
                for (int r = 0; r < 4; ++r) {
                    const float sg = 1.f / (1.f + __expf(-acc[mi][nj][r]));
                    gp[mi][r] = fmaf(sg, wt, gp[mi][r]);
                }
        }
    }
    // reduce partials over the 16 column-lanes, then atomically add to g0
    #pragma unroll
    for (int mi = 0; mi < 4; ++mi)
        #pragma unroll
        for (int r = 0; r < 4; ++r) {
            float v = gp[mi][r];
            v += __shfl_xor(v, 1);
            v += __shfl_xor(v, 2);
            v += __shfl_xor(v, 4);
            v += __shfl_xor(v, 8);
            if (l15 == 0) {
                const int srow = s0 + wm * 64 + mi * 16 + quad * 4 + r;
                if (srow < TM1) atomicAdd(&g0[b * TM1 + srow], v);
            }
        }
}

// --- r[b,0,d] = sum_s xs[b,d,s]*g0[b,s]; r[b,1,d] = Wsum*sum_s xs - r0 ---
__global__ __launch_bounds__(256) void k_r(const float* __restrict__ xs,
                                           const float* __restrict__ g0,
                                           const float* __restrict__ wsum,
                                           float* __restrict__ r) {
    const int d = blockIdx.x;
    const int b = blockIdx.y;
    const float* xrow = xs + ((size_t)b * ND + d) * NT;
    const float* g = g0 + b * TM1;
    float a0 = 0.f, a1 = 0.f;
    for (int s = threadIdx.x; s < TM1; s += 256) {
        const float x = xrow[s];
        a0 = fmaf(x, g[s], a0);
        a1 += x;
    }
    #pragma unroll
    for (int off = 32; off > 0; off >>= 1) {
        a0 += __shfl_down(a0, off);
        a1 += __shfl_down(a1, off);
    }
    __shared__ float l0[4], l1[4];
    const int wid = threadIdx.x >> 6;
    if ((threadIdx.x & 63) == 0) { l0[wid] = a0; l1[wid] = a1; }
    __syncthreads();
    if (threadIdx.x == 0) {
        const float sum0 = l0[0] + l0[1] + l0[2] + l0[3];
        const float sumx = l1[0] + l1[1] + l1[2] + l1[3];
        const float wsv = *wsum;
        r[((size_t)b * 2 + 0) * ND + d] = sum0;
        r[((size_t)b * 2 + 1) * ND + d] = fmaf(wsv, sumx, -sum0);
    }
}

// --- out[b,i] = sum_d W_PV[i,d] * r[b, i/256, d]  (fp32 out) -------------
__global__ __launch_bounds__(256) void k_out(const float* __restrict__ wpv,
                                             const float* __restrict__ r,
                                             float* __restrict__ out) {
    const int b = blockIdx.x;
    __shared__ float rs[1024];
    for (int i = threadIdx.x; i < 1024; i += 256) rs[i] = r[(size_t)b * 1024 + i];
    __syncthreads();
    for (int i = threadIdx.x; i < ND; i += 256) {
        const float* wrow = wpv + (size_t)i * ND;
        const float* rh = rs + (i >> 8) * ND;
        float acc = 0.f;
        for (int dd = 0; dd < ND; dd += 4) {
            const float4 wv = *(const float4*)(wrow + dd);
            acc += wv.x * rh[dd] + wv.y * rh[dd + 1] + wv.z * rh[dd + 2] + wv.w * rh[dd + 3];
        }
        out[b * ND + i] = acc;
    }
}

extern "C" void kernel_launch(void* const* d_in, const int* in_sizes, int n_in,
                              void* d_out, int out_size, void* d_ws, size_t ws_size,
                              hipStream_t stream) {
    (void)in_sizes; (void)n_in; (void)out_size;
    const float* xs   = (const float*)d_in[0];
    const float* wkq  = (const float*)d_in[1];
    const float* wpv  = (const float*)d_in[2];
    const float* wout = (const float*)d_in[3];
    const float* wlast = wout + (size_t)(NT - 1) * NT;  // W_out[-1]

    float* ws   = (float*)d_ws;
    float* g0   = ws + G0_OFF;
    float* wsum = ws + WSUM_OFF;
    float* r    = ws + R_OFF;
    ushort_t* wkqT = (ushort_t*)(ws + WKQT_OFF);

    // Chunk batches: per batch needs 2 MB qdb + 2 MB xst of ws.
    const size_t ws_floats = ws_size / 4;
    size_t avail = (ws_floats > CHUNK_OFF) ? (ws_floats - CHUNK_OFF) : 0;
    int C = (int)(avail / BATCH_FLOATS);
    if (C > NB) C = NB;
    if (C < 1) C = 1;
    ushort_t* qdb = (ushort_t*)(ws + CHUNK_OFF);
    ushort_t* xst = (ushort_t*)(ws + CHUNK_OFF + (size_t)C * 524288ull);

    hipMemsetAsync(g0, 0, G0_ELEMS * sizeof(float), stream);
    k_wsum<<<1, 256, 0, stream>>>(wlast, wsum);
    k_cvt_wkq<<<dim3(16, 16), 256, 0, stream>>>(wkq, wkqT);
    for (int b0 = 0; b0 < NB; b0 += C) {
        const int cb = (NB - b0 < C) ? (NB - b0) : C;
        k_cvt_xst<<<dim3(64, 16, cb), 256, 0, stream>>>(xs, xst, b0);
        k_qd     <<<dim3(4, 16, cb),  256, 0, stream>>>(xst, wkqT, qdb);
        k_attn   <<<dim3(2, 16, cb),  256, 0, stream>>>(qdb, xst, wlast, g0, b0);
    }
    k_r  <<<dim3(ND, NB), 256, 0, stream>>>(xs, g0, wsum, r);
    k_out<<<NB, 256, 0, stream>>>(wpv, r, (float*)d_out);
}

// Round 6
// 339.542 us; speedup vs baseline: 4.0627x; 1.0965x over previous
//
#include <hip/hip_runtime.h>
#include <hip/hip_bf16.h>

// Problem constants
#define NB 16
#define ND 512
#define NT 2048
#define TM1 2047
#define NHD 256

typedef __attribute__((ext_vector_type(8))) short bf16x8;
typedef __attribute__((ext_vector_type(4))) float f32x4;
typedef unsigned short ushort_t;
typedef unsigned int uint_t;

// ws layout (float offsets): head scratch, wkqT, then per-chunk qdb/xst.
#define G0_OFF    0ull
#define G0_ELEMS  (16ull * 2047ull)
#define WSUM_OFF  32752ull
#define R_OFF     32768ull
#define WKQT_OFF  49152ull                 // 512*512 bf16 = 131072 floats
#define CHUNK_OFF 180224ull
#define BATCH_US  (2048ull * 512ull)       // ushorts per batch per array (2 MB)
#define BATCH_FLOATS (2ull * 524288ull)    // qdb + xst floats per batch (4 MB)

__device__ __forceinline__ ushort_t f2bf(float x) {
    union { float f; uint_t u; } v; v.f = x;
    uint_t r = v.u + 0x7FFFu + ((v.u >> 16) & 1u);  // round-to-nearest-even
    return (ushort_t)(r >> 16);
}

// Async global->LDS DMA, 16 B/lane, 1024 B/wave-instruction.
// lds base must be wave-uniform; HW writes lane i's data at base + i*16.
__device__ __forceinline__ void async_copy16(const ushort_t* g, ushort_t* l) {
    __builtin_amdgcn_global_load_lds(
        (const __attribute__((address_space(1))) void*)g,
        (__attribute__((address_space(3))) void*)l, 16, 0, 0);
}

// --- Wsum = sum_t W_out[-1][t] ------------------------------------------
__global__ __launch_bounds__(256) void k_wsum(const float* __restrict__ wlast,
                                              float* __restrict__ wsum) {
    __shared__ float red[256];
    float s = 0.f;
    for (int t = threadIdx.x; t < NT; t += 256) s += wlast[t];
    red[threadIdx.x] = s;
    __syncthreads();
    for (int off = 128; off > 0; off >>= 1) {
        if (threadIdx.x < off) red[threadIdx.x] += red[threadIdx.x + off];
        __syncthreads();
    }
    if (threadIdx.x == 0) *wsum = red[0];
}

// --- wkqT[j][d] = bf16(wkq[d][j]) ---------------------------------------
__global__ __launch_bounds__(256) void k_cvt_wkq(const float* __restrict__ wkq,
                                                 ushort_t* __restrict__ wkqT) {
    __shared__ float tile[32][33];
    const int j0 = blockIdx.x * 32, d0 = blockIdx.y * 32;
    const int c = threadIdx.x & 31, r = threadIdx.x >> 5;  // r in 0..7
    #pragma unroll
    for (int i = 0; i < 4; ++i) {
        const int d = r + i * 8;
        tile[d][c] = wkq[(size_t)(d0 + d) * ND + j0 + c];
    }
    __syncthreads();
    #pragma unroll
    for (int i = 0; i < 4; ++i) {
        const int j = r + i * 8;
        wkqT[(size_t)(j0 + j) * ND + d0 + c] = f2bf(tile[c][j]);
    }
}

// --- xst[c][t][d] = bf16(xs[b0+c][d][t]) --------------------------------
__global__ __launch_bounds__(256) void k_cvt_xst(const float* __restrict__ xs,
                                                 ushort_t* __restrict__ xst, int b0) {
    __shared__ float tile[32][33];
    const int t0 = blockIdx.x * 32, d0 = blockIdx.y * 32;
    const int cc = blockIdx.z;
    const int b = b0 + cc;
    const int c = threadIdx.x & 31, r = threadIdx.x >> 5;
    const float* xb = xs + (size_t)b * ND * NT;
    ushort_t* xo = xst + (size_t)cc * BATCH_US;
    #pragma unroll
    for (int i = 0; i < 4; ++i) {
        const int d = r + i * 8;
        tile[d][c] = xb[(size_t)(d0 + d) * NT + t0 + c];
    }
    __syncthreads();
    #pragma unroll
    for (int i = 0; i < 4; ++i) {
        const int t = r + i * 8;
        xo[(size_t)(t0 + t) * ND + d0 + c] = f2bf(tile[c][t]);
    }
}

// --- qdb[c][s][j] = bf16( sign_j * sum_d xst[c][s][d] * wkqT[j][d] ) -----
// MFMA GEMM, m97 pattern: 128x128/block, K=512 in BK=64 steps,
// global_load_lds staging with XOR chunk swizzle, 4 waves x 64x64.
__global__ __launch_bounds__(256) void k_qd(const ushort_t* __restrict__ xst,
                                            const ushort_t* __restrict__ wkqT,
                                            ushort_t* __restrict__ qdb) {
    const int j0 = blockIdx.x * 128;
    const int s0 = blockIdx.y * 128;
    const int cc = blockIdx.z;
    __shared__ __align__(16) ushort_t As[128 * 64];  // [s][k] swizzled chunks
    __shared__ __align__(16) ushort_t Bs[128 * 64];  // [j][k] swizzled chunks
    const int tid = threadIdx.x;
    const int wave = tid >> 6, lane = tid & 63;
    const int l15 = lane & 15, quad = lane >> 4;
    const int wm = wave >> 1, wn = wave & 1;
    const int swz = l15 & 7;
    // DMA source offset: lane i covers LDS row (i>>3), phys chunk (i&7);
    // phys chunk c holds logical chunk c ^ (row&7) -> lane loads logical (i&7)^(i>>3).
    const int lrow = lane >> 3;
    const size_t lsrc = (size_t)lrow * ND + (size_t)(((lane & 7) ^ lrow) << 3);
    const ushort_t* xa = xst + (size_t)cc * BATCH_US + (size_t)s0 * ND;
    const ushort_t* wb = wkqT + (size_t)j0 * ND;
    ushort_t* qo = qdb + (size_t)cc * BATCH_US;
    f32x4 acc[4][4];
    #pragma unroll
    for (int mi = 0; mi < 4; ++mi)
        #pragma unroll
        for (int nj = 0; nj < 4; ++nj) acc[mi][nj] = (f32x4){0.f, 0.f, 0.f, 0.f};
    for (int ks = 0; ks < 8; ++ks) {
        const int k0 = ks * 64;
        #pragma unroll
        for (int n = 0; n < 4; ++n) {
            const int rbase = wave * 32 + n * 8;     // wave-uniform
            async_copy16(xa + (size_t)rbase * ND + k0 + lsrc, &As[rbase * 64]);
            async_copy16(wb + (size_t)rbase * ND + k0 + lsrc, &Bs[rbase * 64]);
        }
        __builtin_amdgcn_s_waitcnt(0);
        __syncthreads();
        #pragma unroll
        for (int kc = 0; kc < 2; ++kc) {
            bf16x8 af[4], bfr[4];
            #pragma unroll
            for (int mi = 0; mi < 4; ++mi)
                af[mi] = *(const bf16x8*)&As[(wm * 64 + mi * 16 + l15) * 64 + (((kc * 4 + quad) ^ swz) << 3)];
            #pragma unroll
            for (int nj = 0; nj < 4; ++nj)
                bfr[nj] = *(const bf16x8*)&Bs[(wn * 64 + nj * 16 + l15) * 64 + (((kc * 4 + quad) ^ swz) << 3)];
            #pragma unroll
            for (int mi = 0; mi < 4; ++mi)
                #pragma unroll
                for (int nj = 0; nj < 4; ++nj)
                    acc[mi][nj] = __builtin_amdgcn_mfma_f32_16x16x32_bf16(af[mi], bfr[nj], acc[mi][nj], 0, 0, 0);
        }
        __syncthreads();
    }
    // Epilogue: sign by head, store bf16 (C/D: row=quad*4+r, col=l15)
    #pragma unroll
    for (int mi = 0; mi < 4; ++mi) {
        const int srow = s0 + wm * 64 + mi * 16 + quad * 4;
        #pragma unroll
        for (int nj = 0; nj < 4; ++nj) {
            const int jcol = j0 + wn * 64 + nj * 16 + l15;
            const float sgn = (jcol < NHD) ? 1.f : -1.f;
            #pragma unroll
            for (int r = 0; r < 4; ++r)
                qo[(size_t)(srow + r) * ND + jcol] = f2bf(sgn * acc[mi][nj][r]);
        }
    }
}

// --- g0[b,s] += sum_t sigmoid(Delta[b,s,t]) * w[t] -----------------------
// Delta = qdb[s][:] . xst[t][:] (K=512). One 128s x 128t tile per block.
__global__ __launch_bounds__(256) void k_attn(const ushort_t* __restrict__ qdb,
                                              const ushort_t* __restrict__ xst,
                                              const float* __restrict__ wlast,
                                              float* __restrict__ g0, int b0) {
    const int t0 = blockIdx.x * 128;
    const int s0 = blockIdx.y * 128;
    const int cc = blockIdx.z;
    const int b = b0 + cc;
    __shared__ __align__(16) ushort_t As[128 * 64];  // [s][k]
    __shared__ __align__(16) ushort_t Bs[128 * 64];  // [t][k]
    const int tid = threadIdx.x;
    const int wave = tid >> 6, lane = tid & 63;
    const int l15 = lane & 15, quad = lane >> 4;
    const int wm = wave >> 1, wn = wave & 1;
    const int swz = l15 & 7;
    const int lrow = lane >> 3;
    const size_t lsrc = (size_t)lrow * ND + (size_t)(((lane & 7) ^ lrow) << 3);
    const ushort_t* qa = qdb + (size_t)cc * BATCH_US + (size_t)s0 * ND;
    const ushort_t* xa = xst + (size_t)cc * BATCH_US + (size_t)t0 * ND;
    f32x4 acc[4][4];
    #pragma unroll
    for (int mi = 0; mi < 4; ++mi)
        #pragma unroll
        for (int nj = 0; nj < 4; ++nj) acc[mi][nj] = (f32x4){0.f, 0.f, 0.f, 0.f};
    for (int ks = 0; ks < 8; ++ks) {
        const int k0 = ks * 64;
        #pragma unroll
        for (int n = 0; n < 4; ++n) {
            const int rbase = wave * 32 + n * 8;     // wave-uniform
            async_copy16(qa + (size_t)rbase * ND + k0 + lsrc, &As[rbase * 64]);
            async_copy16(xa + (size_t)rbase * ND + k0 + lsrc, &Bs[rbase * 64]);
        }
        __builtin_amdgcn_s_waitcnt(0);
        __syncthreads();
        #pragma unroll
        for (int kc = 0; kc < 2; ++kc) {
            bf16x8 af[4], bfr[4];
            #pragma unroll
            for (int mi = 0; mi < 4; ++mi)
                af[mi] = *(const bf16x8*)&As[(wm * 64 + mi * 16 + l15) * 64 + (((kc * 4 + quad) ^ swz) << 3)];
            #pragma unroll
            for (int nj = 0; nj < 4; ++nj)
                bfr[nj] = *(const bf16x8*)&Bs[(wn * 64 + nj * 16 + l15) * 64 + (((kc * 4 + quad) ^ swz) << 3)];
            #pragma unroll
            for (int mi = 0; mi < 4; ++mi)
                #pragma unroll
                for (int nj = 0; nj < 4; ++nj)
                    acc[mi][nj] = __builtin_amdgcn_mfma_f32_16x16x32_bf16(af[mi], bfr[nj], acc[mi][nj], 0, 0, 0);
        }
        __syncthreads();
    }
    // Epilogue: fold sigmoid * w[t], reduce over the 16 t-lanes, atomicAdd.
    float gp[4][4] = {};
    #pragma unroll
    for (int nj = 0; nj < 4; ++nj) {
        const float wt = wlast[t0 + wn * 64 + nj * 16 + l15];
        #pragma unroll
        for (int mi = 0; mi < 4; ++mi)
            #pragma unroll
            for (int r = 0; r < 4; ++r) {
                const float sg = 1.f / (1.f + __expf(-acc[mi][nj][r]));
                gp[mi][r] = fmaf(sg, wt, gp[mi][r]);
            }
    }
    #pragma unroll
    for (int mi = 0; mi < 4; ++mi)
        #pragma unroll
        for (int r = 0; r < 4; ++r) {
            float v = gp[mi][r];
            v += __shfl_xor(v, 1);
            v += __shfl_xor(v, 2);
            v += __shfl_xor(v, 4);
            v += __shfl_xor(v, 8);
            if (l15 == 0) {
                const int srow = s0 + wm * 64 + mi * 16 + quad * 4 + r;
                if (srow < TM1) atomicAdd(&g0[b * TM1 + srow], v);
            }
        }
}

// --- r[b,0,d] = sum_s xs[b,d,s]*g0[b,s]; r[b,1,d] = Wsum*sum_s xs - r0 ---
__global__ __launch_bounds__(256) void k_r(const float* __restrict__ xs,
                                           const float* __restrict__ g0,
                                           const float* __restrict__ wsum,
                                           float* __restrict__ r) {
    const int d = blockIdx.x;
    const int b = blockIdx.y;
    const float* xrow = xs + ((size_t)b * ND + d) * NT;
    const float* g = g0 + b * TM1;
    float a0 = 0.f, a1 = 0.f;
    for (int s = threadIdx.x; s < TM1; s += 256) {
        const float x = xrow[s];
        a0 = fmaf(x, g[s], a0);
        a1 += x;
    }
    #pragma unroll
    for (int off = 32; off > 0; off >>= 1) {
        a0 += __shfl_down(a0, off);
        a1 += __shfl_down(a1, off);
    }
    __shared__ float l0[4], l1[4];
    const int wid = threadIdx.x >> 6;
    if ((threadIdx.x & 63) == 0) { l0[wid] = a0; l1[wid] = a1; }
    __syncthreads();
    if (threadIdx.x == 0) {
        const float sum0 = l0[0] + l0[1] + l0[2] + l0[3];
        const float sumx = l1[0] + l1[1] + l1[2] + l1[3];
        const float wsv = *wsum;
        r[((size_t)b * 2 + 0) * ND + d] = sum0;
        r[((size_t)b * 2 + 1) * ND + d] = fmaf(wsv, sumx, -sum0);
    }
}

// --- out[b,i] = sum_d W_PV[i,d] * r[b, i/256, d]  (fp32 out) -------------
__global__ __launch_bounds__(256) void k_out(const float* __restrict__ wpv,
                                             const float* __restrict__ r,
                                             float* __restrict__ out) {
    const int b = blockIdx.x;
    __shared__ float rs[1024];
    for (int i = threadIdx.x; i < 1024; i += 256) rs[i] = r[(size_t)b * 1024 + i];
    __syncthreads();
    for (int i = threadIdx.x; i < ND; i += 256) {
        const float* wrow = wpv + (size_t)i * ND;
        const float* rh = rs + (i >> 8) * ND;
        float acc = 0.f;
        for (int dd = 0; dd < ND; dd += 4) {
            const float4 wv = *(const float4*)(wrow + dd);
            acc += wv.x * rh[dd] + wv.y * rh[dd + 1] + wv.z * rh[dd + 2] + wv.w * rh[dd + 3];
        }
        out[b * ND + i] = acc;
    }
}

extern "C" void kernel_launch(void* const* d_in, const int* in_sizes, int n_in,
                              void* d_out, int out_size, void* d_ws, size_t ws_size,
                              hipStream_t stream) {
    (void)in_sizes; (void)n_in; (void)out_size;
    const float* xs   = (const float*)d_in[0];
    const float* wkq  = (const float*)d_in[1];
    const float* wpv  = (const float*)d_in[2];
    const float* wout = (const float*)d_in[3];
    const float* wlast = wout + (size_t)(NT - 1) * NT;  // W_out[-1]

    float* ws   = (float*)d_ws;
    float* g0   = ws + G0_OFF;
    float* wsum = ws + WSUM_OFF;
    float* r    = ws + R_OFF;
    ushort_t* wkqT = (ushort_t*)(ws + WKQT_OFF);

    // Chunk batches: per batch needs 2 MB qdb + 2 MB xst of ws.
    const size_t ws_floats = ws_size / 4;
    size_t avail = (ws_floats > CHUNK_OFF) ? (ws_floats - CHUNK_OFF) : 0;
    int C = (int)(avail / BATCH_FLOATS);
    if (C > NB) C = NB;
    if (C < 1) C = 1;
    ushort_t* qdb = (ushort_t*)(ws + CHUNK_OFF);
    ushort_t* xst = (ushort_t*)(ws + CHUNK_OFF + (size_t)C * 524288ull);

    hipMemsetAsync(g0, 0, G0_ELEMS * sizeof(float), stream);
    k_wsum<<<1, 256, 0, stream>>>(wlast, wsum);
    k_cvt_wkq<<<dim3(16, 16), 256, 0, stream>>>(wkq, wkqT);
    for (int b0 = 0; b0 < NB; b0 += C) {
        const int cb = (NB - b0 < C) ? (NB - b0) : C;
        k_cvt_xst<<<dim3(64, 16, cb), 256, 0, stream>>>(xs, xst, b0);
        k_qd     <<<dim3(4, 16, cb),  256, 0, stream>>>(xst, wkqT, qdb);
        k_attn   <<<dim3(16, 16, cb), 256, 0, stream>>>(qdb, xst, wlast, g0, b0);
    }
    k_r  <<<dim3(ND, NB), 256, 0, stream>>>(xs, g0, wsum, r);
    k_out<<<NB, 256, 0, stream>>>(wpv, r, (float*)d_out);
}

// Round 7
// 310.815 us; speedup vs baseline: 4.4381x; 1.0924x over previous
//
#include <hip/hip_runtime.h>
#include <hip/hip_bf16.h>

// Problem constants
#define NB 16
#define ND 512
#define NT 2048
#define TM1 2047
#define NHD 256

typedef __attribute__((ext_vector_type(8))) short bf16x8;
typedef __attribute__((ext_vector_type(4))) float f32x4;
typedef unsigned short ushort_t;
typedef unsigned int uint_t;

// ws layout (float offsets): head scratch, wkqT, then per-chunk qdb/xst.
#define G0_OFF    0ull
#define G0_ELEMS  (16ull * 2047ull)
#define WSUM_OFF  32752ull
#define R_OFF     32768ull
#define WKQT_OFF  49152ull                 // 512*512 bf16 = 131072 floats
#define CHUNK_OFF 180224ull
#define BATCH_US  (2048ull * 512ull)       // ushorts per batch per array (2 MB)
#define BATCH_FLOATS (2ull * 524288ull)    // qdb + xst floats per batch (4 MB)

__device__ __forceinline__ ushort_t f2bf(float x) {
    union { float f; uint_t u; } v; v.f = x;
    uint_t r = v.u + 0x7FFFu + ((v.u >> 16) & 1u);  // round-to-nearest-even
    return (ushort_t)(r >> 16);
}

// Async global->LDS DMA, 16 B/lane, 1024 B/wave-instruction.
// lds base must be wave-uniform; HW writes lane i's data at base + i*16.
__device__ __forceinline__ void async_copy16(const ushort_t* g, ushort_t* l) {
    __builtin_amdgcn_global_load_lds(
        (const __attribute__((address_space(1))) void*)g,
        (__attribute__((address_space(3))) void*)l, 16, 0, 0);
}

// --- prep: wkqT[j][d] = bf16(wkq[d][j]);  g0 = 0;  wsum = sum(wlast) -----
__global__ __launch_bounds__(256) void k_prep(const float* __restrict__ wkq,
                                              ushort_t* __restrict__ wkqT,
                                              const float* __restrict__ wlast,
                                              float* __restrict__ wsum,
                                              float* __restrict__ g0) {
    __shared__ float tile[32][33];
    const int j0 = blockIdx.x * 32, d0 = blockIdx.y * 32;
    const int c = threadIdx.x & 31, r = threadIdx.x >> 5;  // r in 0..7
    #pragma unroll
    for (int i = 0; i < 4; ++i) {
        const int d = r + i * 8;
        tile[d][c] = wkq[(size_t)(d0 + d) * ND + j0 + c];
    }
    __syncthreads();
    #pragma unroll
    for (int i = 0; i < 4; ++i) {
        const int j = r + i * 8;
        wkqT[(size_t)(j0 + j) * ND + d0 + c] = f2bf(tile[c][j]);
    }
    // zero g0 (32752 floats over 256 blocks)
    const int bid = blockIdx.y * 16 + blockIdx.x;
    if (threadIdx.x < 128) {
        const int idx = bid * 128 + threadIdx.x;
        if (idx < (int)G0_ELEMS) g0[idx] = 0.f;
    }
    // block (0,0) additionally reduces wlast -> wsum
    if (bid == 0) {
        __shared__ float red[256];
        float s = 0.f;
        for (int t = threadIdx.x; t < NT; t += 256) s += wlast[t];
        red[threadIdx.x] = s;
        __syncthreads();
        for (int off = 128; off > 0; off >>= 1) {
            if (threadIdx.x < off) red[threadIdx.x] += red[threadIdx.x + off];
            __syncthreads();
        }
        if (threadIdx.x == 0) *wsum = red[0];
    }
}

// --- xst[c][t][d] = bf16(xs[b0+c][d][t]) --------------------------------
__global__ __launch_bounds__(256) void k_cvt_xst(const float* __restrict__ xs,
                                                 ushort_t* __restrict__ xst, int b0) {
    __shared__ float tile[32][33];
    const int t0 = blockIdx.x * 32, d0 = blockIdx.y * 32;
    const int cc = blockIdx.z;
    const int b = b0 + cc;
    const int c = threadIdx.x & 31, r = threadIdx.x >> 5;
    const float* xb = xs + (size_t)b * ND * NT;
    ushort_t* xo = xst + (size_t)cc * BATCH_US;
    #pragma unroll
    for (int i = 0; i < 4; ++i) {
        const int d = r + i * 8;
        tile[d][c] = xb[(size_t)(d0 + d) * NT + t0 + c];
    }
    __syncthreads();
    #pragma unroll
    for (int i = 0; i < 4; ++i) {
        const int t = r + i * 8;
        xo[(size_t)(t0 + t) * ND + d0 + c] = f2bf(tile[c][t]);
    }
}

// --- qdb[c][s][j] = bf16( sign_j * sum_d xst[c][s][d] * wkqT[j][d] ) -----
// MFMA GEMM, m97 pattern: 128x128/block, K=512 in BK=64 steps,
// global_load_lds staging with XOR chunk swizzle, 4 waves x 64x64.
__global__ __launch_bounds__(256) void k_qd(const ushort_t* __restrict__ xst,
                                            const ushort_t* __restrict__ wkqT,
                                            ushort_t* __restrict__ qdb) {
    const int j0 = blockIdx.x * 128;
    const int s0 = blockIdx.y * 128;
    const int cc = blockIdx.z;
    __shared__ __align__(16) ushort_t As[128 * 64];  // [s][k] swizzled chunks
    __shared__ __align__(16) ushort_t Bs[128 * 64];  // [j][k] swizzled chunks
    const int tid = threadIdx.x;
    const int wave = tid >> 6, lane = tid & 63;
    const int l15 = lane & 15, quad = lane >> 4;
    const int wm = wave >> 1, wn = wave & 1;
    const int swz = l15 & 7;
    const int lrow = lane >> 3;
    const size_t lsrc = (size_t)lrow * ND + (size_t)(((lane & 7) ^ lrow) << 3);
    const ushort_t* xa = xst + (size_t)cc * BATCH_US + (size_t)s0 * ND;
    const ushort_t* wb = wkqT + (size_t)j0 * ND;
    ushort_t* qo = qdb + (size_t)cc * BATCH_US;
    f32x4 acc[4][4];
    #pragma unroll
    for (int mi = 0; mi < 4; ++mi)
        #pragma unroll
        for (int nj = 0; nj < 4; ++nj) acc[mi][nj] = (f32x4){0.f, 0.f, 0.f, 0.f};
    for (int ks = 0; ks < 8; ++ks) {
        const int k0 = ks * 64;
        #pragma unroll
        for (int n = 0; n < 4; ++n) {
            const int rbase = wave * 32 + n * 8;     // wave-uniform
            async_copy16(xa + (size_t)rbase * ND + k0 + lsrc, &As[rbase * 64]);
            async_copy16(wb + (size_t)rbase * ND + k0 + lsrc, &Bs[rbase * 64]);
        }
        __builtin_amdgcn_s_waitcnt(0);
        __syncthreads();
        #pragma unroll
        for (int kc = 0; kc < 2; ++kc) {
            bf16x8 af[4], bfr[4];
            #pragma unroll
            for (int mi = 0; mi < 4; ++mi)
                af[mi] = *(const bf16x8*)&As[(wm * 64 + mi * 16 + l15) * 64 + (((kc * 4 + quad) ^ swz) << 3)];
            #pragma unroll
            for (int nj = 0; nj < 4; ++nj)
                bfr[nj] = *(const bf16x8*)&Bs[(wn * 64 + nj * 16 + l15) * 64 + (((kc * 4 + quad) ^ swz) << 3)];
            #pragma unroll
            for (int mi = 0; mi < 4; ++mi)
                #pragma unroll
                for (int nj = 0; nj < 4; ++nj)
                    acc[mi][nj] = __builtin_amdgcn_mfma_f32_16x16x32_bf16(af[mi], bfr[nj], acc[mi][nj], 0, 0, 0);
        }
        __syncthreads();
    }
    // Epilogue: sign by head, store bf16 (C/D: row=quad*4+r, col=l15)
    #pragma unroll
    for (int mi = 0; mi < 4; ++mi) {
        const int srow = s0 + wm * 64 + mi * 16 + quad * 4;
        #pragma unroll
        for (int nj = 0; nj < 4; ++nj) {
            const int jcol = j0 + wn * 64 + nj * 16 + l15;
            const float sgn = (jcol < NHD) ? 1.f : -1.f;
            #pragma unroll
            for (int r = 0; r < 4; ++r)
                qo[(size_t)(srow + r) * ND + jcol] = f2bf(sgn * acc[mi][nj][r]);
        }
    }
}

// --- g0[b,s] += sum_t sigmoid(Delta[b,s,t]) * w[t] -----------------------
// Delta = qdb[s][:] . xst[t][:] (K=512). One 128s x 128t tile per block.
__global__ __launch_bounds__(256) void k_attn(const ushort_t* __restrict__ qdb,
                                              const ushort_t* __restrict__ xst,
                                              const float* __restrict__ wlast,
                                              float* __restrict__ g0, int b0) {
    const int t0 = blockIdx.x * 128;
    const int s0 = blockIdx.y * 128;
    const int cc = blockIdx.z;
    const int b = b0 + cc;
    __shared__ __align__(16) ushort_t As[128 * 64];  // [s][k]
    __shared__ __align__(16) ushort_t Bs[128 * 64];  // [t][k]
    const int tid = threadIdx.x;
    const int wave = tid >> 6, lane = tid & 63;
    const int l15 = lane & 15, quad = lane >> 4;
    const int wm = wave >> 1, wn = wave & 1;
    const int swz = l15 & 7;
    const int lrow = lane >> 3;
    const size_t lsrc = (size_t)lrow * ND + (size_t)(((lane & 7) ^ lrow) << 3);
    const ushort_t* qa = qdb + (size_t)cc * BATCH_US + (size_t)s0 * ND;
    const ushort_t* xa = xst + (size_t)cc * BATCH_US + (size_t)t0 * ND;
    f32x4 acc[4][4];
    #pragma unroll
    for (int mi = 0; mi < 4; ++mi)
        #pragma unroll
        for (int nj = 0; nj < 4; ++nj) acc[mi][nj] = (f32x4){0.f, 0.f, 0.f, 0.f};
    for (int ks = 0; ks < 8; ++ks) {
        const int k0 = ks * 64;
        #pragma unroll
        for (int n = 0; n < 4; ++n) {
            const int rbase = wave * 32 + n * 8;     // wave-uniform
            async_copy16(qa + (size_t)rbase * ND + k0 + lsrc, &As[rbase * 64]);
            async_copy16(xa + (size_t)rbase * ND + k0 + lsrc, &Bs[rbase * 64]);
        }
        __builtin_amdgcn_s_waitcnt(0);
        __syncthreads();
        #pragma unroll
        for (int kc = 0; kc < 2; ++kc) {
            bf16x8 af[4], bfr[4];
            #pragma unroll
            for (int mi = 0; mi < 4; ++mi)
                af[mi] = *(const bf16x8*)&As[(wm * 64 + mi * 16 + l15) * 64 + (((kc * 4 + quad) ^ swz) << 3)];
            #pragma unroll
            for (int nj = 0; nj < 4; ++nj)
                bfr[nj] = *(const bf16x8*)&Bs[(wn * 64 + nj * 16 + l15) * 64 + (((kc * 4 + quad) ^ swz) << 3)];
            #pragma unroll
            for (int mi = 0; mi < 4; ++mi)
                #pragma unroll
                for (int nj = 0; nj < 4; ++nj)
                    acc[mi][nj] = __builtin_amdgcn_mfma_f32_16x16x32_bf16(af[mi], bfr[nj], acc[mi][nj], 0, 0, 0);
        }
        __syncthreads();
    }
    // Epilogue: fold sigmoid * w[t] (fast path: v_exp + v_rcp, no fp32 div),
    // reduce over the 16 t-lanes, atomicAdd.
    float gp[4][4] = {};
    #pragma unroll
    for (int nj = 0; nj < 4; ++nj) {
        const float wt = wlast[t0 + wn * 64 + nj * 16 + l15];
        #pragma unroll
        for (int mi = 0; mi < 4; ++mi)
            #pragma unroll
            for (int r = 0; r < 4; ++r) {
                const float e = __expf(-acc[mi][nj][r]);
                const float sg = __builtin_amdgcn_rcpf(1.f + e);
                gp[mi][r] = fmaf(sg, wt, gp[mi][r]);
            }
    }
    #pragma unroll
    for (int mi = 0; mi < 4; ++mi)
        #pragma unroll
        for (int r = 0; r < 4; ++r) {
            float v = gp[mi][r];
            v += __shfl_xor(v, 1);
            v += __shfl_xor(v, 2);
            v += __shfl_xor(v, 4);
            v += __shfl_xor(v, 8);
            if (l15 == 0) {
                const int srow = s0 + wm * 64 + mi * 16 + quad * 4 + r;
                if (srow < TM1) atomicAdd(&g0[b * TM1 + srow], v);
            }
        }
}

// --- r[b,0,d] = sum_s xs[b,d,s]*g0[b,s]; r[b,1,d] = Wsum*sum_s xs - r0 ---
__global__ __launch_bounds__(256) void k_r(const float* __restrict__ xs,
                                           const float* __restrict__ g0,
                                           const float* __restrict__ wsum,
                                           float* __restrict__ r) {
    const int d = blockIdx.x;
    const int b = blockIdx.y;
    const float* xrow = xs + ((size_t)b * ND + d) * NT;
    const float* g = g0 + b * TM1;
    float a0 = 0.f, a1 = 0.f;
    for (int s = threadIdx.x; s < TM1; s += 256) {
        const float x = xrow[s];
        a0 = fmaf(x, g[s], a0);
        a1 += x;
    }
    #pragma unroll
    for (int off = 32; off > 0; off >>= 1) {
        a0 += __shfl_down(a0, off);
        a1 += __shfl_down(a1, off);
    }
    __shared__ float l0[4], l1[4];
    const int wid = threadIdx.x >> 6;
    if ((threadIdx.x & 63) == 0) { l0[wid] = a0; l1[wid] = a1; }
    __syncthreads();
    if (threadIdx.x == 0) {
        const float sum0 = l0[0] + l0[1] + l0[2] + l0[3];
        const float sumx = l1[0] + l1[1] + l1[2] + l1[3];
        const float wsv = *wsum;
        r[((size_t)b * 2 + 0) * ND + d] = sum0;
        r[((size_t)b * 2 + 1) * ND + d] = fmaf(wsv, sumx, -sum0);
    }
}

// --- out[b,i] = sum_d W_PV[i,d] * r[b, i/256, d]  (fp32 out) -------------
__global__ __launch_bounds__(256) void k_out(const float* __restrict__ wpv,
                                             const float* __restrict__ r,
                                             float* __restrict__ out) {
    const int b = blockIdx.x;
    __shared__ float rs[1024];
    for (int i = threadIdx.x; i < 1024; i += 256) rs[i] = r[(size_t)b * 1024 + i];
    __syncthreads();
    for (int i = threadIdx.x; i < ND; i += 256) {
        const float* wrow = wpv + (size_t)i * ND;
        const float* rh = rs + (i >> 8) * ND;
        float acc = 0.f;
        for (int dd = 0; dd < ND; dd += 4) {
            const float4 wv = *(const float4*)(wrow + dd);
            acc += wv.x * rh[dd] + wv.y * rh[dd + 1] + wv.z * rh[dd + 2] + wv.w * rh[dd + 3];
        }
        out[b * ND + i] = acc;
    }
}

extern "C" void kernel_launch(void* const* d_in, const int* in_sizes, int n_in,
                              void* d_out, int out_size, void* d_ws, size_t ws_size,
                              hipStream_t stream) {
    (void)in_sizes; (void)n_in; (void)out_size;
    const float* xs   = (const float*)d_in[0];
    const float* wkq  = (const float*)d_in[1];
    const float* wpv  = (const float*)d_in[2];
    const float* wout = (const float*)d_in[3];
    const float* wlast = wout + (size_t)(NT - 1) * NT;  // W_out[-1]

    float* ws   = (float*)d_ws;
    float* g0   = ws + G0_OFF;
    float* wsum = ws + WSUM_OFF;
    float* r    = ws + R_OFF;
    ushort_t* wkqT = (ushort_t*)(ws + WKQT_OFF);

    // Chunk batches: per batch needs 2 MB qdb + 2 MB xst of ws.
    const size_t ws_floats = ws_size / 4;
    size_t avail = (ws_floats > CHUNK_OFF) ? (ws_floats - CHUNK_OFF) : 0;
    int C = (int)(avail / BATCH_FLOATS);
    if (C > NB) C = NB;
    if (C < 1) C = 1;
    ushort_t* qdb = (ushort_t*)(ws + CHUNK_OFF);
    ushort_t* xst = (ushort_t*)(ws + CHUNK_OFF + (size_t)C * 524288ull);

    k_prep<<<dim3(16, 16), 256, 0, stream>>>(wkq, wkqT, wlast, wsum, g0);
    for (int b0 = 0; b0 < NB; b0 += C) {
        const int cb = (NB - b0 < C) ? (NB - b0) : C;
        k_cvt_xst<<<dim3(64, 16, cb), 256, 0, stream>>>(xs, xst, b0);
        k_qd     <<<dim3(4, 16, cb),  256, 0, stream>>>(xst, wkqT, qdb);
        k_attn   <<<dim3(16, 16, cb), 256, 0, stream>>>(qdb, xst, wlast, g0, b0);
    }
    k_r  <<<dim3(ND, NB), 256, 0, stream>>>(xs, g0, wsum, r);
    k_out<<<NB, 256, 0, stream>>>(wpv, r, (float*)d_out);
}